// Round 1
// baseline (128.753 us; speedup 1.0000x reference)
//
#include <hip/hip_runtime.h>
#include <stdint.h>

#define Bn 4096
#define Mn 8192
#define Fn 256
#define HIDn 256
#define Cn 64

typedef float f32x4 __attribute__((ext_vector_type(4)));
typedef short s16x8 __attribute__((ext_vector_type(8)));

__device__ __forceinline__ uint16_t f2bf(float f) {
    union { float f; uint32_t u; } v; v.f = f;
    uint32_t r = v.u + 0x7FFFu + ((v.u >> 16) & 1u);
    return (uint16_t)(r >> 16);
}

// XOR swizzle for LDS tiles with 128B rows: flips bits 4-6 with row&7 (bits 7-9).
__device__ __forceinline__ uint32_t swz(uint32_t o) { return o ^ (((o >> 7) & 7u) << 4); }

// ---------------------------------------------------------------------------
// Prep 1: x[h][b] = self@a_self, y[h][m] = neigh@a_neigh, self_bf16.
__global__ __launch_bounds__(256) void k_prep_xy(
    const float* __restrict__ selff, const float* __restrict__ neigh,
    const float* __restrict__ a, float* __restrict__ x, float* __restrict__ y,
    uint16_t* __restrict__ self_bf)
{
    const int w = threadIdx.x >> 6, l = threadIdx.x & 63;
    const int r = blockIdx.x * 4 + w;             // 0..B+M-1
    const bool is_self = (r < Bn);
    const float* row = is_self ? (selff + (size_t)r * Fn) : (neigh + (size_t)(r - Bn) * Fn);
    const int aoff = is_self ? 0 : Fn;
    const float4 v  = *(const float4*)(row + l * 4);
    const float4 c0 = *(const float4*)(a + aoff + l * 4);            // a[0, aoff+f, 0]
    const float4 c1 = *(const float4*)(a + 2 * Fn + aoff + l * 4);   // a[1, aoff+f, 0]
    float d0 = v.x * c0.x + v.y * c0.y + v.z * c0.z + v.w * c0.w;
    float d1 = v.x * c1.x + v.y * c1.y + v.z * c1.z + v.w * c1.w;
    #pragma unroll
    for (int s = 32; s > 0; s >>= 1) { d0 += __shfl_xor(d0, s); d1 += __shfl_xor(d1, s); }
    if (is_self) {
        uint2 pk;
        pk.x = (uint32_t)f2bf(v.x) | ((uint32_t)f2bf(v.y) << 16);
        pk.y = (uint32_t)f2bf(v.z) | ((uint32_t)f2bf(v.w) << 16);
        *(uint2*)(self_bf + (size_t)r * Fn + l * 4) = pk;
        if (l == 0) { x[r] = d0; x[Bn + r] = d1; }
    } else {
        const int m = r - Bn;
        if (l == 0) { y[m] = d0; y[Mn + m] = d1; }
    }
}

// ---------------------------------------------------------------------------
// Prep 2: neighT_bf16[f][m] = bf16(neigh[m][f])  (for MFMA B-operand reads)
__global__ __launch_bounds__(256) void k_tn(const float* __restrict__ neigh, uint16_t* __restrict__ neighT)
{
    __shared__ float tl[32][33];
    const int tx = threadIdx.x & 31, ty = threadIdx.x >> 5;
    const int m0 = blockIdx.x * 32, f0 = blockIdx.y * 32;
    #pragma unroll
    for (int i = 0; i < 4; ++i)
        tl[ty + 8 * i][tx] = neigh[(size_t)(m0 + ty + 8 * i) * Fn + f0 + tx];
    __syncthreads();
    #pragma unroll
    for (int i = 0; i < 4; ++i)
        neighT[(size_t)(f0 + ty + 8 * i) * Mn + m0 + tx] = f2bf(tl[tx][ty + 8 * i]);
}

// ---------------------------------------------------------------------------
// Prep 3: enc_wT[h][n][k] = bf16(enc_w[h][k][n]); out_wT[n][k] = bf16(out_w[k][n])
__global__ __launch_bounds__(256) void k_prep_w(const float* __restrict__ enc_w, const float* __restrict__ out_w,
                                                uint16_t* __restrict__ enc_wT, uint16_t* __restrict__ out_wT)
{
    const int tid = blockIdx.x * 256 + threadIdx.x;
    if (tid < 2 * HIDn * 512) {
        const int h = tid >> 17;
        const int rr = tid & 131071;
        const int n = rr >> 9, k = rr & 511;
        enc_wT[tid] = f2bf(enc_w[(size_t)h * 512 * HIDn + (size_t)k * HIDn + n]);
    } else {
        const int rr = tid - 2 * HIDn * 512;   // 0..32767
        const int n = rr >> 9, k = rr & 511;
        out_wT[rr] = f2bf(out_w[(size_t)k * Cn + n]);
    }
}

// ---------------------------------------------------------------------------
// Main fused kernel: U[h][b][f] += sum_m mask*exp(lrelu(x+y)) * neigh[m][f]
//                    Z[h][b]    += sum_m mask*exp(lrelu(x+y))
// Block: 64 rows (b) x full F=256, both heads, K-chunk of 2048 m's.
// Grid (64, 4). 512 threads = 8 waves: waves 0-3 head0 (n0 = w*64), 4-7 head1.
__global__ __launch_bounds__(512) void k_main(
    const float* __restrict__ mask, const float* __restrict__ x, const float* __restrict__ y,
    const uint16_t* __restrict__ neighT, float* __restrict__ U, float* __restrict__ Z)
{
    __shared__ uint16_t ldsB[Fn * 64];      // [f][m] bf16, 32 KB, swizzled
    __shared__ uint16_t ldsP[2 * 64 * 64];  // [h][b][m] bf16, 16 KB, swizzled
    const int t = threadIdx.x;
    const int w = t >> 6, l = t & 63;
    const int b0 = blockIdx.x * 64;
    const int mbase = blockIdx.y * 2048;

    // P-build mapping: each thread owns row pb, 8 consecutive m's, BOTH heads.
    const int pb = t >> 3;
    const int pm = (t & 7) * 8;
    const float x0 = x[b0 + pb];
    const float x1 = x[Bn + b0 + pb];
    float z0 = 0.f, z1 = 0.f;

    const int hw = w >> 2;
    const int n0 = (w & 3) * 64;

    f32x4 acc[4][4];
    #pragma unroll
    for (int i = 0; i < 4; ++i)
        #pragma unroll
        for (int j = 0; j < 4; ++j)
            acc[i][j] = (f32x4){0.f, 0.f, 0.f, 0.f};

    char* ldsBw = (char*)ldsB;
    char* ldsPw = (char*)ldsP;
    const float* mrow = mask + (size_t)(b0 + pb) * Mn + mbase + pm;
    const float* y0p = y + mbase + pm;
    const float* y1p = y + Mn + mbase + pm;
    const uint32_t pwo = swz((uint32_t)(pb * 128 + pm * 2));

    for (int kt = 0; kt < 32; ++kt) {
        // ---- stage neighT tile [256 f][64 m] (reg-staged, swizzled dest)
        #pragma unroll
        for (int i = 0; i < 4; ++i) {
            const uint32_t o = (uint32_t)(i * 8192 + t * 16);
            const uint32_t fr = o >> 7, mb = o & 127u;
            const uint4 d = *(const uint4*)((const char*)neighT + ((size_t)fr * Mn + mbase) * 2 + (size_t)kt * 128 + mb);
            *(uint4*)(ldsBw + swz(o)) = d;
        }
        // ---- build P tile for both heads; accumulate Z partials in regs
        {
            const int mo = kt * 64;
            const float4 mA  = *(const float4*)(mrow + mo);
            const float4 mB  = *(const float4*)(mrow + mo + 4);
            const float4 yA0 = *(const float4*)(y0p + mo);
            const float4 yA1 = *(const float4*)(y0p + mo + 4);
            const float4 yB0 = *(const float4*)(y1p + mo);
            const float4 yB1 = *(const float4*)(y1p + mo + 4);
            float mk[8]  = {mA.x, mA.y, mA.z, mA.w, mB.x, mB.y, mB.z, mB.w};
            float yv0[8] = {yA0.x, yA0.y, yA0.z, yA0.w, yA1.x, yA1.y, yA1.z, yA1.w};
            float yv1[8] = {yB0.x, yB0.y, yB0.z, yB0.w, yB1.x, yB1.y, yB1.z, yB1.w};
            uint16_t p0[8], p1[8];
            #pragma unroll
            for (int j = 0; j < 8; ++j) {
                float t0 = x0 + yv0[j];
                float s0 = fmaxf(t0, 0.2f * t0);          // leaky_relu
                float e0 = mk[j] * __expf(s0);            // mask in {0,1}
                z0 += e0; p0[j] = f2bf(e0);
                float t1 = x1 + yv1[j];
                float s1 = fmaxf(t1, 0.2f * t1);
                float e1 = mk[j] * __expf(s1);
                z1 += e1; p1[j] = f2bf(e1);
            }
            uint4 q0, q1;
            q0.x = p0[0] | ((uint32_t)p0[1] << 16); q0.y = p0[2] | ((uint32_t)p0[3] << 16);
            q0.z = p0[4] | ((uint32_t)p0[5] << 16); q0.w = p0[6] | ((uint32_t)p0[7] << 16);
            q1.x = p1[0] | ((uint32_t)p1[1] << 16); q1.y = p1[2] | ((uint32_t)p1[3] << 16);
            q1.z = p1[4] | ((uint32_t)p1[5] << 16); q1.w = p1[6] | ((uint32_t)p1[7] << 16);
            *(uint4*)(ldsPw + pwo) = q0;
            *(uint4*)(ldsPw + 8192 + pwo) = q1;
        }
        __syncthreads();
        // ---- MFMA: acc += P_tile @ neigh_tile
        #pragma unroll
        for (int kk = 0; kk < 2; ++kk) {
            const uint32_t kb = (uint32_t)((kk * 32 + (l >> 4) * 8) * 2);
            s16x8 af[4], bfr[4];
            #pragma unroll
            for (int i = 0; i < 4; ++i) {
                const uint32_t ar = (uint32_t)(i * 16 + (l & 15));
                af[i] = *(const s16x8*)((const char*)ldsP + hw * 8192 + swz(ar * 128 + kb));
            }
            #pragma unroll
            for (int j = 0; j < 4; ++j) {
                const uint32_t br = (uint32_t)(n0 + j * 16 + (l & 15));
                bfr[j] = *(const s16x8*)((const char*)ldsB + swz(br * 128 + kb));
            }
            #pragma unroll
            for (int i = 0; i < 4; ++i)
                #pragma unroll
                for (int j = 0; j < 4; ++j)
                    acc[i][j] = __builtin_amdgcn_mfma_f32_16x16x32_bf16(af[i], bfr[j], acc[i][j], 0, 0, 0);
        }
        __syncthreads();
    }

    // Z: reduce over the 8 threads sharing a row, one atomic per (h, b) per block.
    z0 += __shfl_xor(z0, 1); z0 += __shfl_xor(z0, 2); z0 += __shfl_xor(z0, 4);
    z1 += __shfl_xor(z1, 1); z1 += __shfl_xor(z1, 2); z1 += __shfl_xor(z1, 4);
    if ((t & 7) == 0) {
        atomicAdd(&Z[b0 + pb], z0);
        atomicAdd(&Z[Bn + b0 + pb], z1);
    }
    // U: K-split accumulation via f32 atomics.
    float* Uh = U + (size_t)hw * Bn * Fn;
    #pragma unroll
    for (int i = 0; i < 4; ++i)
        #pragma unroll
        for (int j = 0; j < 4; ++j)
            #pragma unroll
            for (int r = 0; r < 4; ++r) {
                const int row = i * 16 + (l >> 4) * 4 + r;
                const int col = n0 + j * 16 + (l & 15);
                atomicAdd(&Uh[(size_t)(b0 + row) * Fn + col], acc[i][j][r]);
            }
}

// ---------------------------------------------------------------------------
// agg_bf16[h][b][f] = bf16(U/Z)
__global__ __launch_bounds__(256) void k_agg(const float* __restrict__ U, const float* __restrict__ Z,
                                             uint16_t* __restrict__ agg)
{
    const int gid = blockIdx.x * 256 + threadIdx.x;
    const int rb = gid >> 5;            // h*4096 + b
    const int f0 = (gid & 31) * 8;
    const float zi = 1.0f / Z[rb];
    const float4 u0 = *(const float4*)(U + (size_t)rb * Fn + f0);
    const float4 u1 = *(const float4*)(U + (size_t)rb * Fn + f0 + 4);
    uint4 pk;
    pk.x = f2bf(u0.x * zi) | ((uint32_t)f2bf(u0.y * zi) << 16);
    pk.y = f2bf(u0.z * zi) | ((uint32_t)f2bf(u0.w * zi) << 16);
    pk.z = f2bf(u1.x * zi) | ((uint32_t)f2bf(u1.y * zi) << 16);
    pk.w = f2bf(u1.z * zi) | ((uint32_t)f2bf(u1.w * zi) << 16);
    *(uint4*)(agg + (size_t)rb * Fn + f0) = pk;
}

// ---------------------------------------------------------------------------
// enc[b][h*256+n] = relu([self | agg_h] @ enc_w[h]) , bf16 out.
// Grid (32, 2, 2): 128 rows x 128 cols per block, K=512 (k<256: self, else agg).
__global__ __launch_bounds__(512) void k_enc(
    const uint16_t* __restrict__ self_bf, const uint16_t* __restrict__ agg,
    const uint16_t* __restrict__ enc_wT, uint16_t* __restrict__ enc)
{
    __shared__ uint16_t ldsA[128 * 64];
    __shared__ uint16_t ldsW[128 * 64];
    const int t = threadIdx.x, w = t >> 6, l = t & 63;
    const int b0 = blockIdx.x * 128;
    const int nblk = blockIdx.y * 128;
    const int h = blockIdx.z;
    const int wr = (w >> 2) * 64;
    const int wc = (w & 3) * 32;
    f32x4 acc[4][2];
    #pragma unroll
    for (int i = 0; i < 4; ++i)
        #pragma unroll
        for (int j = 0; j < 2; ++j)
            acc[i][j] = (f32x4){0.f, 0.f, 0.f, 0.f};

    const uint16_t* aggh = agg + (size_t)h * Bn * Fn;
    const char* Bsrc = (const char*)(enc_wT + (size_t)h * HIDn * 512);

    for (int kt = 0; kt < 8; ++kt) {
        const char* Ak = (const char*)((kt < 4) ? self_bf : aggh) + (kt & 3) * 128;
        #pragma unroll
        for (int i = 0; i < 2; ++i) {
            const uint32_t o = (uint32_t)(i * 8192 + t * 16);
            const uint32_t rr = o >> 7, kb = o & 127u;
            const uint4 da = *(const uint4*)(Ak + (size_t)(b0 + rr) * 512 + kb);
            *(uint4*)((char*)ldsA + swz(o)) = da;
            const uint4 db = *(const uint4*)(Bsrc + (size_t)(nblk + rr) * 1024 + kt * 128 + kb);
            *(uint4*)((char*)ldsW + swz(o)) = db;
        }
        __syncthreads();
        #pragma unroll
        for (int kk = 0; kk < 2; ++kk) {
            const uint32_t kb = (uint32_t)((kk * 32 + (l >> 4) * 8) * 2);
            s16x8 af[4], bw[2];
            #pragma unroll
            for (int i = 0; i < 4; ++i) {
                const uint32_t ar = (uint32_t)(wr + i * 16 + (l & 15));
                af[i] = *(const s16x8*)((const char*)ldsA + swz(ar * 128 + kb));
            }
            #pragma unroll
            for (int j = 0; j < 2; ++j) {
                const uint32_t br = (uint32_t)(wc + j * 16 + (l & 15));
                bw[j] = *(const s16x8*)((const char*)ldsW + swz(br * 128 + kb));
            }
            #pragma unroll
            for (int i = 0; i < 4; ++i)
                #pragma unroll
                for (int j = 0; j < 2; ++j)
                    acc[i][j] = __builtin_amdgcn_mfma_f32_16x16x32_bf16(af[i], bw[j], acc[i][j], 0, 0, 0);
        }
        __syncthreads();
    }
    #pragma unroll
    for (int i = 0; i < 4; ++i)
        #pragma unroll
        for (int j = 0; j < 2; ++j)
            #pragma unroll
            for (int r = 0; r < 4; ++r) {
                const int row = wr + i * 16 + (l >> 4) * 4 + r;
                const int col = nblk + wc + j * 16 + (l & 15);
                enc[(size_t)(b0 + row) * 512 + h * HIDn + col] = f2bf(fmaxf(acc[i][j][r], 0.f));
            }
}

// ---------------------------------------------------------------------------
// out[b][c] = enc @ out_w  (f32 out). Grid (64): 64 rows x 64 cols, K=512.
__global__ __launch_bounds__(256) void k_out(
    const uint16_t* __restrict__ enc, const uint16_t* __restrict__ out_wT, float* __restrict__ out)
{
    __shared__ uint16_t ldsA[64 * 64];
    __shared__ uint16_t ldsW[64 * 64];
    const int t = threadIdx.x, w = t >> 6, l = t & 63;
    const int b0 = blockIdx.x * 64;
    const int wr = w * 16;
    f32x4 acc[4];
    #pragma unroll
    for (int j = 0; j < 4; ++j) acc[j] = (f32x4){0.f, 0.f, 0.f, 0.f};

    for (int kt = 0; kt < 8; ++kt) {
        #pragma unroll
        for (int i = 0; i < 2; ++i) {
            const uint32_t o = (uint32_t)(i * 4096 + t * 16);
            const uint32_t rr = o >> 7, kb = o & 127u;
            const uint4 da = *(const uint4*)((const char*)enc + (size_t)(b0 + rr) * 1024 + kt * 128 + kb);
            *(uint4*)((char*)ldsA + swz(o)) = da;
            const uint4 db = *(const uint4*)((const char*)out_wT + (size_t)rr * 1024 + kt * 128 + kb);
            *(uint4*)((char*)ldsW + swz(o)) = db;
        }
        __syncthreads();
        #pragma unroll
        for (int kk = 0; kk < 2; ++kk) {
            const uint32_t kb = (uint32_t)((kk * 32 + (l >> 4) * 8) * 2);
            const uint32_t ar = (uint32_t)(wr + (l & 15));
            const s16x8 af = *(const s16x8*)((const char*)ldsA + swz(ar * 128 + kb));
            #pragma unroll
            for (int j = 0; j < 4; ++j) {
                const uint32_t br = (uint32_t)(j * 16 + (l & 15));
                const s16x8 bw = *(const s16x8*)((const char*)ldsW + swz(br * 128 + kb));
                acc[j] = __builtin_amdgcn_mfma_f32_16x16x32_bf16(af, bw, acc[j], 0, 0, 0);
            }
        }
        __syncthreads();
    }
    #pragma unroll
    for (int j = 0; j < 4; ++j)
        #pragma unroll
        for (int r = 0; r < 4; ++r) {
            const int row = wr + (l >> 4) * 4 + r;
            const int col = j * 16 + (l & 15);
            out[(size_t)(b0 + row) * Cn + col] = acc[j][r];
        }
}

// ---------------------------------------------------------------------------
extern "C" void kernel_launch(void* const* d_in, const int* in_sizes, int n_in,
                              void* d_out, int out_size, void* d_ws, size_t ws_size,
                              hipStream_t stream) {
    const float* self_feats = (const float*)d_in[0];
    const float* neigh      = (const float*)d_in[1];
    const float* mask       = (const float*)d_in[2];
    const float* a          = (const float*)d_in[3];
    const float* enc_w      = (const float*)d_in[4];
    const float* out_w      = (const float*)d_in[5];
    float* out = (float*)d_out;

    char* ws = (char*)d_ws;
    size_t off = 0;
    auto alloc = [&](size_t bytes) { char* p = ws + off; off += (bytes + 255) & ~(size_t)255; return p; };
    float*    U       = (float*)alloc((size_t)2 * Bn * Fn * 4);    // 8 MB
    float*    Z       = (float*)alloc((size_t)2 * Bn * 4);
    float*    x       = (float*)alloc((size_t)2 * Bn * 4);
    float*    y       = (float*)alloc((size_t)2 * Mn * 4);
    uint16_t* neighT  = (uint16_t*)alloc((size_t)Fn * Mn * 2);     // 4 MB
    uint16_t* self_bf = (uint16_t*)alloc((size_t)Bn * Fn * 2);     // 2 MB
    uint16_t* agg_bf  = (uint16_t*)alloc((size_t)2 * Bn * Fn * 2); // 4 MB
    uint16_t* enc     = (uint16_t*)alloc((size_t)Bn * 512 * 2);    // 4 MB
    uint16_t* enc_wT  = (uint16_t*)alloc((size_t)2 * HIDn * 512 * 2);
    uint16_t* out_wT  = (uint16_t*)alloc((size_t)Cn * 512 * 2);

    hipMemsetAsync(U, 0, (size_t)2 * Bn * Fn * 4, stream);
    hipMemsetAsync(Z, 0, (size_t)2 * Bn * 4, stream);

    k_prep_xy<<<(Bn + Mn) / 4, 256, 0, stream>>>(self_feats, neigh, a, x, y, self_bf);
    k_tn<<<dim3(Mn / 32, Fn / 32), 256, 0, stream>>>(neigh, neighT);
    k_prep_w<<<(2 * HIDn * 512 + Cn * 512) / 256, 256, 0, stream>>>(enc_w, out_w, enc_wT, out_wT);
    k_main<<<dim3(Bn / 64, 4), 512, 0, stream>>>(mask, x, y, neighT, U, Z);
    k_agg<<<(2 * Bn * Fn / 8) / 256, 256, 0, stream>>>(U, Z, agg_bf);
    k_enc<<<dim3(Bn / 128, 2, 2), 512, 0, stream>>>(self_bf, agg_bf, enc_wT, enc);
    k_out<<<Bn / 64, 256, 0, stream>>>(enc, out_wT, out);
}

// Round 2
// 124.581 us; speedup vs baseline: 1.0335x; 1.0335x over previous
//
#include <hip/hip_runtime.h>
#include <stdint.h>

#define Bn 4096
#define Mn 8192
#define Fn 256
#define HIDn 256
#define Cn 64

typedef float f32x4 __attribute__((ext_vector_type(4)));
typedef short s16x8 __attribute__((ext_vector_type(8)));

__device__ __forceinline__ uint16_t f2bf(float f) {
    union { float f; uint32_t u; } v; v.f = f;
    uint32_t r = v.u + 0x7FFFu + ((v.u >> 16) & 1u);
    return (uint16_t)(r >> 16);
}

// XOR swizzle for LDS tiles with 128B rows: flips bits 4-6 with row&7 (bits 7-9). Involution.
__device__ __forceinline__ uint32_t swz(uint32_t o) { return o ^ (((o >> 7) & 7u) << 4); }

__device__ __forceinline__ void glds16(const char* g, char* l) {
    __builtin_amdgcn_global_load_lds(
        (const __attribute__((address_space(1))) void*)g,
        (__attribute__((address_space(3))) void*)l, 16, 0, 0);
}

// ---------------------------------------------------------------------------
// Prep 1: x[h][b] = self@a_self, y[h][m] = neigh@a_neigh, self_bf16.
__global__ __launch_bounds__(256) void k_prep_xy(
    const float* __restrict__ selff, const float* __restrict__ neigh,
    const float* __restrict__ a, float* __restrict__ x, float* __restrict__ y,
    uint16_t* __restrict__ self_bf)
{
    const int w = threadIdx.x >> 6, l = threadIdx.x & 63;
    const int r = blockIdx.x * 4 + w;             // 0..B+M-1
    const bool is_self = (r < Bn);
    const float* row = is_self ? (selff + (size_t)r * Fn) : (neigh + (size_t)(r - Bn) * Fn);
    const int aoff = is_self ? 0 : Fn;
    const float4 v  = *(const float4*)(row + l * 4);
    const float4 c0 = *(const float4*)(a + aoff + l * 4);            // a[0, aoff+f, 0]
    const float4 c1 = *(const float4*)(a + 2 * Fn + aoff + l * 4);   // a[1, aoff+f, 0]
    float d0 = v.x * c0.x + v.y * c0.y + v.z * c0.z + v.w * c0.w;
    float d1 = v.x * c1.x + v.y * c1.y + v.z * c1.z + v.w * c1.w;
    #pragma unroll
    for (int s = 32; s > 0; s >>= 1) { d0 += __shfl_xor(d0, s); d1 += __shfl_xor(d1, s); }
    if (is_self) {
        uint2 pk;
        pk.x = (uint32_t)f2bf(v.x) | ((uint32_t)f2bf(v.y) << 16);
        pk.y = (uint32_t)f2bf(v.z) | ((uint32_t)f2bf(v.w) << 16);
        *(uint2*)(self_bf + (size_t)r * Fn + l * 4) = pk;
        if (l == 0) { x[r] = d0; x[Bn + r] = d1; }
    } else {
        const int m = r - Bn;
        if (l == 0) { y[m] = d0; y[Mn + m] = d1; }
    }
}

// ---------------------------------------------------------------------------
// Prep 2: neighTg: tiled + pre-swizzled bf16 transpose of neigh.
// Layout: tile = m>>6 (128 tiles of 32KB); within tile, element (f, m&63) at
// byte offset swz(f*128 + (m&63)*2). k_main copies tiles linearly via
// global_load_lds and reads LDS at swz(o) -> gets element (f, m) (rule #21).
__global__ __launch_bounds__(256) void k_tn(const float* __restrict__ neigh, char* __restrict__ neighTg)
{
    __shared__ float tl[32][33];
    const int tx = threadIdx.x & 31, ty = threadIdx.x >> 5;
    const int m0 = blockIdx.x * 32, f0 = blockIdx.y * 32;
    #pragma unroll
    for (int i = 0; i < 4; ++i)
        tl[ty + 8 * i][tx] = neigh[(size_t)(m0 + ty + 8 * i) * Fn + f0 + tx];
    __syncthreads();
    #pragma unroll
    for (int i = 0; i < 4; ++i) {
        const int f = f0 + ty + 8 * i;
        const int m = m0 + tx;
        const uint32_t o = (uint32_t)(f * 128 + (m & 63) * 2);
        *(uint16_t*)(neighTg + (size_t)(m >> 6) * 32768 + swz(o)) = f2bf(tl[tx][ty + 8 * i]);
    }
}

// ---------------------------------------------------------------------------
// Prep 3: enc_wT[h][n][k] = bf16(enc_w[h][k][n]); out_wT[n][k] = bf16(out_w[k][n])
__global__ __launch_bounds__(256) void k_prep_w(const float* __restrict__ enc_w, const float* __restrict__ out_w,
                                                uint16_t* __restrict__ enc_wT, uint16_t* __restrict__ out_wT)
{
    const int tid = blockIdx.x * 256 + threadIdx.x;
    if (tid < 2 * HIDn * 512) {
        const int h = tid >> 17;
        const int rr = tid & 131071;
        const int n = rr >> 9, k = rr & 511;
        enc_wT[tid] = f2bf(enc_w[(size_t)h * 512 * HIDn + (size_t)k * HIDn + n]);
    } else {
        const int rr = tid - 2 * HIDn * 512;   // 0..32767
        const int n = rr >> 9, k = rr & 511;
        out_wT[rr] = f2bf(out_w[(size_t)k * Cn + n]);
    }
}

// ---------------------------------------------------------------------------
// Main fused kernel: U[h][b][f] += sum_m mask*exp(lrelu(x+y)) * neigh[m][f]
//                    Z[h][b]    += sum_m mask*exp(lrelu(x+y))
// 64 rows x F=256, both heads, K-chunk 2048. Grid (64,4) = 256 blocks = 1/CU.
// Pipelined: dbuf LDS (B 2x32KB via global_load_lds, P 2x16KB), one raw
// s_barrier per K-step, counted vmcnt(10) keeps next tile's loads in flight.
__global__ __launch_bounds__(512) void k_main(
    const float* __restrict__ mask, const float* __restrict__ x, const float* __restrict__ y,
    const char* __restrict__ neighTg, float* __restrict__ U, float* __restrict__ Z)
{
    __shared__ __align__(16) uint16_t ldsB[2][Fn * 64];      // 2 x 32KB, [f][m] swizzled
    __shared__ __align__(16) uint16_t ldsP[2][2 * 64 * 64];  // 2 x 16KB, [h][b][m] swizzled
    const int t = threadIdx.x;
    const int w = t >> 6, l = t & 63;
    const int b0 = blockIdx.x * 64;
    const int mbase = blockIdx.y * 2048;
    const int tile0 = blockIdx.y * 32;

    // P-build mapping: thread owns row pb, 8 consecutive m's, BOTH heads.
    const int pb = t >> 3;
    const int pm = (t & 7) * 8;
    const float x0 = x[b0 + pb];
    const float x1 = x[Bn + b0 + pb];
    float z0 = 0.f, z1 = 0.f;

    const int hw = w >> 2;          // head of this wave
    const int n0 = (w & 3) * 64;    // F-column block of this wave

    f32x4 acc[4][4];
    #pragma unroll
    for (int i = 0; i < 4; ++i)
        #pragma unroll
        for (int j = 0; j < 4; ++j)
            acc[i][j] = (f32x4){0.f, 0.f, 0.f, 0.f};

    const float* mrow = mask + (size_t)(b0 + pb) * Mn + mbase + pm;
    const float* y0p = y + mbase + pm;
    const float* y1p = y + Mn + mbase + pm;
    const uint32_t pwo = swz((uint32_t)(pb * 128 + pm * 2));
    const uint32_t gchunk = (uint32_t)(w * 4096);   // 4KB of the 32KB tile per wave

    auto stage = [&](int kt, int buf) {
        const char* gb = neighTg + (size_t)(tile0 + kt) * 32768 + gchunk + (uint32_t)(l * 16);
        char* lb = (char*)ldsB[buf] + gchunk;       // wave-uniform; HW adds lane*16
        #pragma unroll
        for (int c = 0; c < 4; ++c)
            glds16(gb + c * 1024, lb + c * 1024);
    };
    auto loadmy = [&](int kt, float4* mv, float4* ya, float4* yb) {
        const int mo = kt * 64;
        mv[0] = *(const float4*)(mrow + mo); mv[1] = *(const float4*)(mrow + mo + 4);
        ya[0] = *(const float4*)(y0p + mo);  ya[1] = *(const float4*)(y0p + mo + 4);
        yb[0] = *(const float4*)(y1p + mo);  yb[1] = *(const float4*)(y1p + mo + 4);
    };
    auto buildP = [&](int buf, const float4* mv, const float4* ya, const float4* yb) {
        float mk[8]  = {mv[0].x, mv[0].y, mv[0].z, mv[0].w, mv[1].x, mv[1].y, mv[1].z, mv[1].w};
        float yv0[8] = {ya[0].x, ya[0].y, ya[0].z, ya[0].w, ya[1].x, ya[1].y, ya[1].z, ya[1].w};
        float yv1[8] = {yb[0].x, yb[0].y, yb[0].z, yb[0].w, yb[1].x, yb[1].y, yb[1].z, yb[1].w};
        uint16_t p0[8], p1[8];
        #pragma unroll
        for (int j = 0; j < 8; ++j) {
            float t0 = x0 + yv0[j];
            float s0 = fmaxf(t0, 0.2f * t0);
            float e0 = mk[j] * __expf(s0);
            z0 += e0; p0[j] = f2bf(e0);
            float t1 = x1 + yv1[j];
            float s1 = fmaxf(t1, 0.2f * t1);
            float e1 = mk[j] * __expf(s1);
            z1 += e1; p1[j] = f2bf(e1);
        }
        uint4 q0, q1;
        q0.x = p0[0] | ((uint32_t)p0[1] << 16); q0.y = p0[2] | ((uint32_t)p0[3] << 16);
        q0.z = p0[4] | ((uint32_t)p0[5] << 16); q0.w = p0[6] | ((uint32_t)p0[7] << 16);
        q1.x = p1[0] | ((uint32_t)p1[1] << 16); q1.y = p1[2] | ((uint32_t)p1[3] << 16);
        q1.z = p1[4] | ((uint32_t)p1[5] << 16); q1.w = p1[6] | ((uint32_t)p1[7] << 16);
        char* pw = (char*)ldsP[buf];
        *(uint4*)(pw + pwo) = q0;
        *(uint4*)(pw + 8192 + pwo) = q1;
    };
    auto mfma_step = [&](int buf) {
        const char* pA = (const char*)ldsP[buf] + hw * 8192;
        const char* pB = (const char*)ldsB[buf];
        #pragma unroll
        for (int kk = 0; kk < 2; ++kk) {
            const uint32_t kb = (uint32_t)((kk * 32 + (l >> 4) * 8) * 2);
            s16x8 af[4], bfr[4];
            #pragma unroll
            for (int i = 0; i < 4; ++i) {
                const uint32_t ar = (uint32_t)(i * 16 + (l & 15));
                af[i] = *(const s16x8*)(pA + swz(ar * 128 + kb));
            }
            #pragma unroll
            for (int j = 0; j < 4; ++j) {
                const uint32_t br = (uint32_t)(n0 + j * 16 + (l & 15));
                bfr[j] = *(const s16x8*)(pB + swz(br * 128 + kb));
            }
            #pragma unroll
            for (int i = 0; i < 4; ++i)
                #pragma unroll
                for (int j = 0; j < 4; ++j)
                    acc[i][j] = __builtin_amdgcn_mfma_f32_16x16x32_bf16(af[i], bfr[j], acc[i][j], 0, 0, 0);
        }
    };

    // ---- prologue: P(0) -> buf0, B(0) -> buf0 (glds left in flight)
    float4 mc[2], yac[2], ybc[2];
    loadmy(0, mc, yac, ybc);
    buildP(0, mc, yac, ybc);
    stage(0, 0);
    asm volatile("s_waitcnt lgkmcnt(0)" ::: "memory");
    __builtin_amdgcn_s_barrier();

    // ---- main loop: entering iter kt, outstanding vmem = [glds4(B[cur])]
    for (int kt = 0; kt < 31; ++kt) {
        const int cur = kt & 1, nxt = cur ^ 1;
        float4 mn_[2], yan[2], ybn[2];
        loadmy(kt + 1, mn_, yan, ybn);      // 6 vmem loads
        stage(kt + 1, nxt);                 // 4 glds
        // drain the oldest 4 (B[cur]); keep this iter's 10 in flight
        asm volatile("s_waitcnt vmcnt(10)" ::: "memory");
        mfma_step(cur);
        buildP(nxt, mn_, yan, ybn);         // compiler waits vmcnt(4) for mask/y
        asm volatile("s_waitcnt lgkmcnt(0)" ::: "memory");
        __builtin_amdgcn_s_barrier();
    }
    asm volatile("s_waitcnt vmcnt(0)" ::: "memory");
    mfma_step(31 & 1);

    // Z: reduce over the 8 threads sharing a row, one atomic per (h,b) per block.
    z0 += __shfl_xor(z0, 1); z0 += __shfl_xor(z0, 2); z0 += __shfl_xor(z0, 4);
    z1 += __shfl_xor(z1, 1); z1 += __shfl_xor(z1, 2); z1 += __shfl_xor(z1, 4);
    if ((t & 7) == 0) {
        atomicAdd(&Z[b0 + pb], z0);
        atomicAdd(&Z[Bn + b0 + pb], z1);
    }
    // U: K-split accumulation via f32 atomics.
    float* Uh = U + (size_t)hw * Bn * Fn;
    #pragma unroll
    for (int i = 0; i < 4; ++i)
        #pragma unroll
        for (int j = 0; j < 4; ++j)
            #pragma unroll
            for (int r = 0; r < 4; ++r) {
                const int row = i * 16 + (l >> 4) * 4 + r;
                const int col = n0 + j * 16 + (l & 15);
                atomicAdd(&Uh[(size_t)(b0 + row) * Fn + col], acc[i][j][r]);
            }
}

// ---------------------------------------------------------------------------
// agg_bf16[h][b][f] = bf16(U/Z)
__global__ __launch_bounds__(256) void k_agg(const float* __restrict__ U, const float* __restrict__ Z,
                                             uint16_t* __restrict__ agg)
{
    const int gid = blockIdx.x * 256 + threadIdx.x;
    const int rb = gid >> 5;            // h*4096 + b
    const int f0 = (gid & 31) * 8;
    const float zi = 1.0f / Z[rb];
    const float4 u0 = *(const float4*)(U + (size_t)rb * Fn + f0);
    const float4 u1 = *(const float4*)(U + (size_t)rb * Fn + f0 + 4);
    uint4 pk;
    pk.x = f2bf(u0.x * zi) | ((uint32_t)f2bf(u0.y * zi) << 16);
    pk.y = f2bf(u0.z * zi) | ((uint32_t)f2bf(u0.w * zi) << 16);
    pk.z = f2bf(u1.x * zi) | ((uint32_t)f2bf(u1.y * zi) << 16);
    pk.w = f2bf(u1.z * zi) | ((uint32_t)f2bf(u1.w * zi) << 16);
    *(uint4*)(agg + (size_t)rb * Fn + f0) = pk;
}

// ---------------------------------------------------------------------------
// enc[b][h*256+n] = relu([self | agg_h] @ enc_w[h]) , bf16 out.
__global__ __launch_bounds__(512) void k_enc(
    const uint16_t* __restrict__ self_bf, const uint16_t* __restrict__ agg,
    const uint16_t* __restrict__ enc_wT, uint16_t* __restrict__ enc)
{
    __shared__ uint16_t ldsA[128 * 64];
    __shared__ uint16_t ldsW[128 * 64];
    const int t = threadIdx.x, w = t >> 6, l = t & 63;
    const int b0 = blockIdx.x * 128;
    const int nblk = blockIdx.y * 128;
    const int h = blockIdx.z;
    const int wr = (w >> 2) * 64;
    const int wc = (w & 3) * 32;
    f32x4 acc[4][2];
    #pragma unroll
    for (int i = 0; i < 4; ++i)
        #pragma unroll
        for (int j = 0; j < 2; ++j)
            acc[i][j] = (f32x4){0.f, 0.f, 0.f, 0.f};

    const uint16_t* aggh = agg + (size_t)h * Bn * Fn;
    const char* Bsrc = (const char*)(enc_wT + (size_t)h * HIDn * 512);

    for (int kt = 0; kt < 8; ++kt) {
        const char* Ak = (const char*)((kt < 4) ? self_bf : aggh) + (kt & 3) * 128;
        #pragma unroll
        for (int i = 0; i < 2; ++i) {
            const uint32_t o = (uint32_t)(i * 8192 + t * 16);
            const uint32_t rr = o >> 7, kb = o & 127u;
            const uint4 da = *(const uint4*)(Ak + (size_t)(b0 + rr) * 512 + kb);
            *(uint4*)((char*)ldsA + swz(o)) = da;
            const uint4 db = *(const uint4*)(Bsrc + (size_t)(nblk + rr) * 1024 + kt * 128 + kb);
            *(uint4*)((char*)ldsW + swz(o)) = db;
        }
        __syncthreads();
        #pragma unroll
        for (int kk = 0; kk < 2; ++kk) {
            const uint32_t kb = (uint32_t)((kk * 32 + (l >> 4) * 8) * 2);
            s16x8 af[4], bw[2];
            #pragma unroll
            for (int i = 0; i < 4; ++i) {
                const uint32_t ar = (uint32_t)(wr + i * 16 + (l & 15));
                af[i] = *(const s16x8*)((const char*)ldsA + swz(ar * 128 + kb));
            }
            #pragma unroll
            for (int j = 0; j < 2; ++j) {
                const uint32_t br = (uint32_t)(wc + j * 16 + (l & 15));
                bw[j] = *(const s16x8*)((const char*)ldsW + swz(br * 128 + kb));
            }
            #pragma unroll
            for (int i = 0; i < 4; ++i)
                #pragma unroll
                for (int j = 0; j < 2; ++j)
                    acc[i][j] = __builtin_amdgcn_mfma_f32_16x16x32_bf16(af[i], bw[j], acc[i][j], 0, 0, 0);
        }
        __syncthreads();
    }
    #pragma unroll
    for (int i = 0; i < 4; ++i)
        #pragma unroll
        for (int j = 0; j < 2; ++j)
            #pragma unroll
            for (int r = 0; r < 4; ++r) {
                const int row = wr + i * 16 + (l >> 4) * 4 + r;
                const int col = nblk + wc + j * 16 + (l & 15);
                enc[(size_t)(b0 + row) * 512 + h * HIDn + col] = f2bf(fmaxf(acc[i][j][r], 0.f));
            }
}

// ---------------------------------------------------------------------------
// out[b][c] = enc @ out_w  (f32 out). Grid (64): 64 rows x 64 cols, K=512.
__global__ __launch_bounds__(256) void k_out(
    const uint16_t* __restrict__ enc, const uint16_t* __restrict__ out_wT, float* __restrict__ out)
{
    __shared__ uint16_t ldsA[64 * 64];
    __shared__ uint16_t ldsW[64 * 64];
    const int t = threadIdx.x, w = t >> 6, l = t & 63;
    const int b0 = blockIdx.x * 64;
    const int wr = w * 16;
    f32x4 acc[4];
    #pragma unroll
    for (int j = 0; j < 4; ++j) acc[j] = (f32x4){0.f, 0.f, 0.f, 0.f};

    for (int kt = 0; kt < 8; ++kt) {
        #pragma unroll
        for (int i = 0; i < 2; ++i) {
            const uint32_t o = (uint32_t)(i * 4096 + t * 16);
            const uint32_t rr = o >> 7, kb = o & 127u;
            const uint4 da = *(const uint4*)((const char*)enc + (size_t)(b0 + rr) * 1024 + kt * 128 + kb);
            *(uint4*)((char*)ldsA + swz(o)) = da;
            const uint4 db = *(const uint4*)((const char*)out_wT + (size_t)rr * 1024 + kt * 128 + kb);
            *(uint4*)((char*)ldsW + swz(o)) = db;
        }
        __syncthreads();
        #pragma unroll
        for (int kk = 0; kk < 2; ++kk) {
            const uint32_t kb = (uint32_t)((kk * 32 + (l >> 4) * 8) * 2);
            const uint32_t ar = (uint32_t)(wr + (l & 15));
            const s16x8 af = *(const s16x8*)((const char*)ldsA + swz(ar * 128 + kb));
            #pragma unroll
            for (int j = 0; j < 4; ++j) {
                const uint32_t br = (uint32_t)(j * 16 + (l & 15));
                const s16x8 bw = *(const s16x8*)((const char*)ldsW + swz(br * 128 + kb));
                acc[j] = __builtin_amdgcn_mfma_f32_16x16x32_bf16(af, bw, acc[j], 0, 0, 0);
            }
        }
        __syncthreads();
    }
    #pragma unroll
    for (int j = 0; j < 4; ++j)
        #pragma unroll
        for (int r = 0; r < 4; ++r) {
            const int row = wr + (l >> 4) * 4 + r;
            const int col = j * 16 + (l & 15);
            out[(size_t)(b0 + row) * Cn + col] = acc[j][r];
        }
}

// ---------------------------------------------------------------------------
extern "C" void kernel_launch(void* const* d_in, const int* in_sizes, int n_in,
                              void* d_out, int out_size, void* d_ws, size_t ws_size,
                              hipStream_t stream) {
    const float* self_feats = (const float*)d_in[0];
    const float* neigh      = (const float*)d_in[1];
    const float* mask       = (const float*)d_in[2];
    const float* a          = (const float*)d_in[3];
    const float* enc_w      = (const float*)d_in[4];
    const float* out_w      = (const float*)d_in[5];
    float* out = (float*)d_out;

    char* ws = (char*)d_ws;
    size_t off = 0;
    auto alloc = [&](size_t bytes) { char* p = ws + off; off += (bytes + 255) & ~(size_t)255; return p; };
    float*    U       = (float*)alloc((size_t)2 * Bn * Fn * 4);    // 8 MB
    float*    Z       = (float*)alloc((size_t)2 * Bn * 4);         // contiguous after U
    float*    x       = (float*)alloc((size_t)2 * Bn * 4);
    float*    y       = (float*)alloc((size_t)2 * Mn * 4);
    char*     neighTg = (char*)alloc((size_t)Fn * Mn * 2);         // 4 MB, tiled+swizzled
    uint16_t* self_bf = (uint16_t*)alloc((size_t)Bn * Fn * 2);     // 2 MB
    uint16_t* agg_bf  = (uint16_t*)alloc((size_t)2 * Bn * Fn * 2); // 4 MB
    uint16_t* enc     = (uint16_t*)alloc((size_t)Bn * 512 * 2);    // 4 MB
    uint16_t* enc_wT  = (uint16_t*)alloc((size_t)2 * HIDn * 512 * 2);
    uint16_t* out_wT  = (uint16_t*)alloc((size_t)Cn * 512 * 2);

    // U and Z are contiguous: one memset covers both.
    hipMemsetAsync(U, 0, (size_t)2 * Bn * Fn * 4 + (size_t)2 * Bn * 4, stream);

    k_prep_xy<<<(Bn + Mn) / 4, 256, 0, stream>>>(self_feats, neigh, a, x, y, self_bf);
    k_tn<<<dim3(Mn / 32, Fn / 32), 256, 0, stream>>>(neigh, neighTg);
    k_prep_w<<<(2 * HIDn * 512 + Cn * 512) / 256, 256, 0, stream>>>(enc_w, out_w, enc_wT, out_wT);
    k_main<<<dim3(Bn / 64, 4), 512, 0, stream>>>(mask, x, y, neighTg, U, Z);
    k_agg<<<(2 * Bn * Fn / 8) / 256, 256, 0, stream>>>(U, Z, agg_bf);
    k_enc<<<dim3(Bn / 128, 2, 2), 512, 0, stream>>>(self_bf, agg_bf, enc_wT, enc);
    k_out<<<Bn / 64, 256, 0, stream>>>(enc, out_wT, out);
}

// Round 3
// 104.868 us; speedup vs baseline: 1.2278x; 1.1880x over previous
//
#include <hip/hip_runtime.h>
#include <stdint.h>

#define Bn 4096
#define Mn 8192
#define Fn 256
#define HIDn 256
#define Cn 64

typedef float f32x4 __attribute__((ext_vector_type(4)));
typedef short s16x8 __attribute__((ext_vector_type(8)));

__device__ __forceinline__ uint16_t f2bf(float f) {
    union { float f; uint32_t u; } v; v.f = f;
    uint32_t r = v.u + 0x7FFFu + ((v.u >> 16) & 1u);
    return (uint16_t)(r >> 16);
}

// XOR swizzle for LDS tiles with 128B rows: flips bits 4-6 with row&7 (bits 7-9). Involution.
__device__ __forceinline__ uint32_t swz(uint32_t o) { return o ^ (((o >> 7) & 7u) << 4); }

__device__ __forceinline__ void glds16(const char* g, char* l) {
    __builtin_amdgcn_global_load_lds(
        (const __attribute__((address_space(1))) void*)g,
        (__attribute__((address_space(3))) void*)l, 16, 0, 0);
}

// ---------------------------------------------------------------------------
// Prep 1: x[h][b] = self@a_self, y[h][m] = neigh@a_neigh, self_bf16.
__global__ __launch_bounds__(256) void k_prep_xy(
    const float* __restrict__ selff, const float* __restrict__ neigh,
    const float* __restrict__ a, float* __restrict__ x, float* __restrict__ y,
    uint16_t* __restrict__ self_bf)
{
    const int w = threadIdx.x >> 6, l = threadIdx.x & 63;
    const int r = blockIdx.x * 4 + w;             // 0..B+M-1
    const bool is_self = (r < Bn);
    const float* row = is_self ? (selff + (size_t)r * Fn) : (neigh + (size_t)(r - Bn) * Fn);
    const int aoff = is_self ? 0 : Fn;
    const float4 v  = *(const float4*)(row + l * 4);
    const float4 c0 = *(const float4*)(a + aoff + l * 4);            // a[0, aoff+f, 0]
    const float4 c1 = *(const float4*)(a + 2 * Fn + aoff + l * 4);   // a[1, aoff+f, 0]
    float d0 = v.x * c0.x + v.y * c0.y + v.z * c0.z + v.w * c0.w;
    float d1 = v.x * c1.x + v.y * c1.y + v.z * c1.z + v.w * c1.w;
    #pragma unroll
    for (int s = 32; s > 0; s >>= 1) { d0 += __shfl_xor(d0, s); d1 += __shfl_xor(d1, s); }
    if (is_self) {
        uint2 pk;
        pk.x = (uint32_t)f2bf(v.x) | ((uint32_t)f2bf(v.y) << 16);
        pk.y = (uint32_t)f2bf(v.z) | ((uint32_t)f2bf(v.w) << 16);
        *(uint2*)(self_bf + (size_t)r * Fn + l * 4) = pk;
        if (l == 0) { x[r] = d0; x[Bn + r] = d1; }
    } else {
        const int m = r - Bn;
        if (l == 0) { y[m] = d0; y[Mn + m] = d1; }
    }
}

// ---------------------------------------------------------------------------
// Prep 2: neighTg: tiled + pre-swizzled bf16 transpose of neigh.
// Layout: tile = m>>6 (128 tiles of 32KB); within tile, element (f, m&63) at
// byte offset swz(f*128 + (m&63)*2). k_main copies tiles linearly via
// global_load_lds and reads LDS at swz(o) -> gets element (f, m) (rule #21).
__global__ __launch_bounds__(256) void k_tn(const float* __restrict__ neigh, char* __restrict__ neighTg)
{
    __shared__ float tl[32][33];
    const int tx = threadIdx.x & 31, ty = threadIdx.x >> 5;
    const int m0 = blockIdx.x * 32, f0 = blockIdx.y * 32;
    #pragma unroll
    for (int i = 0; i < 4; ++i)
        tl[ty + 8 * i][tx] = neigh[(size_t)(m0 + ty + 8 * i) * Fn + f0 + tx];
    __syncthreads();
    #pragma unroll
    for (int i = 0; i < 4; ++i) {
        const int f = f0 + ty + 8 * i;
        const int m = m0 + tx;
        const uint32_t o = (uint32_t)(f * 128 + (m & 63) * 2);
        *(uint16_t*)(neighTg + (size_t)(m >> 6) * 32768 + swz(o)) = f2bf(tl[tx][ty + 8 * i]);
    }
}

// ---------------------------------------------------------------------------
// Prep 3: enc_wT[h][n][k] = bf16(enc_w[h][k][n]); out_wT[n][k] = bf16(out_w[k][n])
__global__ __launch_bounds__(256) void k_prep_w(const float* __restrict__ enc_w, const float* __restrict__ out_w,
                                                uint16_t* __restrict__ enc_wT, uint16_t* __restrict__ out_wT)
{
    const int tid = blockIdx.x * 256 + threadIdx.x;
    if (tid < 2 * HIDn * 512) {
        const int h = tid >> 17;
        const int rr = tid & 131071;
        const int n = rr >> 9, k = rr & 511;
        enc_wT[tid] = f2bf(enc_w[(size_t)h * 512 * HIDn + (size_t)k * HIDn + n]);
    } else {
        const int rr = tid - 2 * HIDn * 512;   // 0..32767
        const int n = rr >> 9, k = rr & 511;
        out_wT[rr] = f2bf(out_w[(size_t)k * Cn + n]);
    }
}

// ---------------------------------------------------------------------------
// Main fused kernel: Upart[ky][h][b][f] = sum_{m in chunk} mask*exp(lrelu(x+y)) * neigh[m][f]
//                    Z4[ky][h][b]       = sum_{m in chunk} mask*exp(lrelu(x+y))
// 64 rows x F=256, both heads, K-chunk 2048. Grid (64,4) = 256 blocks = 1/CU.
// Plain private-partial stores (NO atomics — cross-XCD atomic contention was
// the ~90us tail in rounds 1-2).
__global__ __launch_bounds__(512) void k_main(
    const float* __restrict__ mask, const float* __restrict__ x, const float* __restrict__ y,
    const char* __restrict__ neighTg, float* __restrict__ Upart, float* __restrict__ Z4)
{
    __shared__ __align__(16) uint16_t ldsB[2][Fn * 64];      // 2 x 32KB, [f][m] swizzled
    __shared__ __align__(16) uint16_t ldsP[2][2 * 64 * 64];  // 2 x 16KB, [h][b][m] swizzled
    const int t = threadIdx.x;
    const int w = t >> 6, l = t & 63;
    const int b0 = blockIdx.x * 64;
    const int ky = blockIdx.y;
    const int mbase = ky * 2048;
    const int tile0 = ky * 32;

    // P-build mapping: thread owns row pb, 8 consecutive m's, BOTH heads.
    const int pb = t >> 3;
    const int pm = (t & 7) * 8;
    const float x0 = x[b0 + pb];
    const float x1 = x[Bn + b0 + pb];
    float z0 = 0.f, z1 = 0.f;

    const int hw = w >> 2;          // head of this wave
    const int n0 = (w & 3) * 64;    // F-column block of this wave

    f32x4 acc[4][4];
    #pragma unroll
    for (int i = 0; i < 4; ++i)
        #pragma unroll
        for (int j = 0; j < 4; ++j)
            acc[i][j] = (f32x4){0.f, 0.f, 0.f, 0.f};

    const float* mrow = mask + (size_t)(b0 + pb) * Mn + mbase + pm;
    const float* y0p = y + mbase + pm;
    const float* y1p = y + Mn + mbase + pm;
    const uint32_t pwo = swz((uint32_t)(pb * 128 + pm * 2));
    const uint32_t gchunk = (uint32_t)(w * 4096);   // 4KB of the 32KB tile per wave

    auto stage = [&](int kt, int buf) {
        const char* gb = neighTg + (size_t)(tile0 + kt) * 32768 + gchunk + (uint32_t)(l * 16);
        char* lb = (char*)ldsB[buf] + gchunk;       // wave-uniform; HW adds lane*16
        #pragma unroll
        for (int c = 0; c < 4; ++c)
            glds16(gb + c * 1024, lb + c * 1024);
    };
    auto loadmy = [&](int kt, float4* mv, float4* ya, float4* yb) {
        const int mo = kt * 64;
        mv[0] = *(const float4*)(mrow + mo); mv[1] = *(const float4*)(mrow + mo + 4);
        ya[0] = *(const float4*)(y0p + mo);  ya[1] = *(const float4*)(y0p + mo + 4);
        yb[0] = *(const float4*)(y1p + mo);  yb[1] = *(const float4*)(y1p + mo + 4);
    };
    auto buildP = [&](int buf, const float4* mv, const float4* ya, const float4* yb) {
        float mk[8]  = {mv[0].x, mv[0].y, mv[0].z, mv[0].w, mv[1].x, mv[1].y, mv[1].z, mv[1].w};
        float yv0[8] = {ya[0].x, ya[0].y, ya[0].z, ya[0].w, ya[1].x, ya[1].y, ya[1].z, ya[1].w};
        float yv1[8] = {yb[0].x, yb[0].y, yb[0].z, yb[0].w, yb[1].x, yb[1].y, yb[1].z, yb[1].w};
        uint16_t p0[8], p1[8];
        #pragma unroll
        for (int j = 0; j < 8; ++j) {
            float t0 = x0 + yv0[j];
            float s0 = fmaxf(t0, 0.2f * t0);
            float e0 = mk[j] * __expf(s0);
            z0 += e0; p0[j] = f2bf(e0);
            float t1 = x1 + yv1[j];
            float s1 = fmaxf(t1, 0.2f * t1);
            float e1 = mk[j] * __expf(s1);
            z1 += e1; p1[j] = f2bf(e1);
        }
        uint4 q0, q1;
        q0.x = p0[0] | ((uint32_t)p0[1] << 16); q0.y = p0[2] | ((uint32_t)p0[3] << 16);
        q0.z = p0[4] | ((uint32_t)p0[5] << 16); q0.w = p0[6] | ((uint32_t)p0[7] << 16);
        q1.x = p1[0] | ((uint32_t)p1[1] << 16); q1.y = p1[2] | ((uint32_t)p1[3] << 16);
        q1.z = p1[4] | ((uint32_t)p1[5] << 16); q1.w = p1[6] | ((uint32_t)p1[7] << 16);
        char* pw = (char*)ldsP[buf];
        *(uint4*)(pw + pwo) = q0;
        *(uint4*)(pw + 8192 + pwo) = q1;
    };
    auto mfma_step = [&](int buf) {
        const char* pA = (const char*)ldsP[buf] + hw * 8192;
        const char* pB = (const char*)ldsB[buf];
        #pragma unroll
        for (int kk = 0; kk < 2; ++kk) {
            const uint32_t kb = (uint32_t)((kk * 32 + (l >> 4) * 8) * 2);
            s16x8 af[4], bfr[4];
            #pragma unroll
            for (int i = 0; i < 4; ++i) {
                const uint32_t ar = (uint32_t)(i * 16 + (l & 15));
                af[i] = *(const s16x8*)(pA + swz(ar * 128 + kb));
            }
            #pragma unroll
            for (int j = 0; j < 4; ++j) {
                const uint32_t br = (uint32_t)(n0 + j * 16 + (l & 15));
                bfr[j] = *(const s16x8*)(pB + swz(br * 128 + kb));
            }
            #pragma unroll
            for (int i = 0; i < 4; ++i)
                #pragma unroll
                for (int j = 0; j < 4; ++j)
                    acc[i][j] = __builtin_amdgcn_mfma_f32_16x16x32_bf16(af[i], bfr[j], acc[i][j], 0, 0, 0);
        }
    };

    // ---- prologue: P(0) -> buf0, B(0) -> buf0 (glds left in flight)
    float4 mc[2], yac[2], ybc[2];
    loadmy(0, mc, yac, ybc);
    buildP(0, mc, yac, ybc);
    stage(0, 0);
    asm volatile("s_waitcnt lgkmcnt(0)" ::: "memory");
    __builtin_amdgcn_s_barrier();

    // ---- main loop: entering iter kt, outstanding vmem = [glds4(B[cur])]
    for (int kt = 0; kt < 31; ++kt) {
        const int cur = kt & 1, nxt = cur ^ 1;
        float4 mn_[2], yan[2], ybn[2];
        loadmy(kt + 1, mn_, yan, ybn);      // 6 vmem loads
        stage(kt + 1, nxt);                 // 4 glds
        // drain the oldest 4 (B[cur]); keep this iter's 10 in flight
        asm volatile("s_waitcnt vmcnt(10)" ::: "memory");
        mfma_step(cur);
        buildP(nxt, mn_, yan, ybn);         // compiler waits vmcnt(4) for mask/y
        asm volatile("s_waitcnt lgkmcnt(0)" ::: "memory");
        __builtin_amdgcn_s_barrier();
    }
    asm volatile("s_waitcnt vmcnt(0)" ::: "memory");
    mfma_step(31 & 1);

    // Z partials: reduce over the 8 threads sharing a row, one plain store each.
    z0 += __shfl_xor(z0, 1); z0 += __shfl_xor(z0, 2); z0 += __shfl_xor(z0, 4);
    z1 += __shfl_xor(z1, 1); z1 += __shfl_xor(z1, 2); z1 += __shfl_xor(z1, 4);
    if ((t & 7) == 0) {
        Z4[(size_t)(ky * 2 + 0) * Bn + b0 + pb] = z0;
        Z4[(size_t)(ky * 2 + 1) * Bn + b0 + pb] = z1;
    }
    // U partials: private per-block slice, plain coalesced stores.
    float* Up = Upart + ((size_t)(ky * 2 + hw) * Bn + b0) * Fn;
    #pragma unroll
    for (int i = 0; i < 4; ++i)
        #pragma unroll
        for (int j = 0; j < 4; ++j)
            #pragma unroll
            for (int r = 0; r < 4; ++r) {
                const int row = i * 16 + (l >> 4) * 4 + r;
                const int col = n0 + j * 16 + (l & 15);
                Up[(size_t)row * Fn + col] = acc[i][j][r];
            }
}

// ---------------------------------------------------------------------------
// agg_bf16[h][b][f] = bf16( (sum_ky Upart[ky][h][b][f]) / (sum_ky Z4[ky][h][b]) )
__global__ __launch_bounds__(256) void k_agg(const float* __restrict__ Upart, const float* __restrict__ Z4,
                                             uint16_t* __restrict__ agg)
{
    const int gid = blockIdx.x * 256 + threadIdx.x;
    const int rb = gid >> 5;            // h*4096 + b
    const int h = rb >> 12, b = rb & 4095;
    const int f0 = (gid & 31) * 8;
    float zs = 0.f;
    #pragma unroll
    for (int ky = 0; ky < 4; ++ky) zs += Z4[(size_t)(ky * 2 + h) * Bn + b];
    const float zi = 1.0f / zs;
    f32x4 u0 = (f32x4){0.f,0.f,0.f,0.f}, u1 = (f32x4){0.f,0.f,0.f,0.f};
    #pragma unroll
    for (int ky = 0; ky < 4; ++ky) {
        const float* up = Upart + ((size_t)(ky * 2 + h) * Bn + b) * Fn + f0;
        const f32x4 a0 = *(const f32x4*)up;
        const f32x4 a1 = *(const f32x4*)(up + 4);
        u0 += a0; u1 += a1;
    }
    uint4 pk;
    pk.x = f2bf(u0[0] * zi) | ((uint32_t)f2bf(u0[1] * zi) << 16);
    pk.y = f2bf(u0[2] * zi) | ((uint32_t)f2bf(u0[3] * zi) << 16);
    pk.z = f2bf(u1[0] * zi) | ((uint32_t)f2bf(u1[1] * zi) << 16);
    pk.w = f2bf(u1[2] * zi) | ((uint32_t)f2bf(u1[3] * zi) << 16);
    *(uint4*)(agg + (size_t)rb * Fn + f0) = pk;
}

// ---------------------------------------------------------------------------
// enc[b][h*256+n] = relu([self | agg_h] @ enc_w[h]) , bf16 out.
__global__ __launch_bounds__(512) void k_enc(
    const uint16_t* __restrict__ self_bf, const uint16_t* __restrict__ agg,
    const uint16_t* __restrict__ enc_wT, uint16_t* __restrict__ enc)
{
    __shared__ uint16_t ldsA[128 * 64];
    __shared__ uint16_t ldsW[128 * 64];
    const int t = threadIdx.x, w = t >> 6, l = t & 63;
    const int b0 = blockIdx.x * 128;
    const int nblk = blockIdx.y * 128;
    const int h = blockIdx.z;
    const int wr = (w >> 2) * 64;
    const int wc = (w & 3) * 32;
    f32x4 acc[4][2];
    #pragma unroll
    for (int i = 0; i < 4; ++i)
        #pragma unroll
        for (int j = 0; j < 2; ++j)
            acc[i][j] = (f32x4){0.f, 0.f, 0.f, 0.f};

    const uint16_t* aggh = agg + (size_t)h * Bn * Fn;
    const char* Bsrc = (const char*)(enc_wT + (size_t)h * HIDn * 512);

    for (int kt = 0; kt < 8; ++kt) {
        const char* Ak = (const char*)((kt < 4) ? self_bf : aggh) + (kt & 3) * 128;
        #pragma unroll
        for (int i = 0; i < 2; ++i) {
            const uint32_t o = (uint32_t)(i * 8192 + t * 16);
            const uint32_t rr = o >> 7, kb = o & 127u;
            const uint4 da = *(const uint4*)(Ak + (size_t)(b0 + rr) * 512 + kb);
            *(uint4*)((char*)ldsA + swz(o)) = da;
            const uint4 db = *(const uint4*)(Bsrc + (size_t)(nblk + rr) * 1024 + kt * 128 + kb);
            *(uint4*)((char*)ldsW + swz(o)) = db;
        }
        __syncthreads();
        #pragma unroll
        for (int kk = 0; kk < 2; ++kk) {
            const uint32_t kb = (uint32_t)((kk * 32 + (l >> 4) * 8) * 2);
            s16x8 af[4], bw[2];
            #pragma unroll
            for (int i = 0; i < 4; ++i) {
                const uint32_t ar = (uint32_t)(wr + i * 16 + (l & 15));
                af[i] = *(const s16x8*)((const char*)ldsA + swz(ar * 128 + kb));
            }
            #pragma unroll
            for (int j = 0; j < 2; ++j) {
                const uint32_t br = (uint32_t)(wc + j * 16 + (l & 15));
                bw[j] = *(const s16x8*)((const char*)ldsW + swz(br * 128 + kb));
            }
            #pragma unroll
            for (int i = 0; i < 4; ++i)
                #pragma unroll
                for (int j = 0; j < 2; ++j)
                    acc[i][j] = __builtin_amdgcn_mfma_f32_16x16x32_bf16(af[i], bw[j], acc[i][j], 0, 0, 0);
        }
        __syncthreads();
    }
    #pragma unroll
    for (int i = 0; i < 4; ++i)
        #pragma unroll
        for (int j = 0; j < 2; ++j)
            #pragma unroll
            for (int r = 0; r < 4; ++r) {
                const int row = wr + i * 16 + (l >> 4) * 4 + r;
                const int col = nblk + wc + j * 16 + (l & 15);
                enc[(size_t)(b0 + row) * 512 + h * HIDn + col] = f2bf(fmaxf(acc[i][j][r], 0.f));
            }
}

// ---------------------------------------------------------------------------
// out[b][c] = enc @ out_w  (f32 out). Grid (64): 64 rows x 64 cols, K=512.
__global__ __launch_bounds__(256) void k_out(
    const uint16_t* __restrict__ enc, const uint16_t* __restrict__ out_wT, float* __restrict__ out)
{
    __shared__ uint16_t ldsA[64 * 64];
    __shared__ uint16_t ldsW[64 * 64];
    const int t = threadIdx.x, w = t >> 6, l = t & 63;
    const int b0 = blockIdx.x * 64;
    const int wr = w * 16;
    f32x4 acc[4];
    #pragma unroll
    for (int j = 0; j < 4; ++j) acc[j] = (f32x4){0.f, 0.f, 0.f, 0.f};

    for (int kt = 0; kt < 8; ++kt) {
        #pragma unroll
        for (int i = 0; i < 2; ++i) {
            const uint32_t o = (uint32_t)(i * 4096 + t * 16);
            const uint32_t rr = o >> 7, kb = o & 127u;
            const uint4 da = *(const uint4*)((const char*)enc + (size_t)(b0 + rr) * 1024 + kt * 128 + kb);
            *(uint4*)((char*)ldsA + swz(o)) = da;
            const uint4 db = *(const uint4*)((const char*)out_wT + (size_t)rr * 1024 + kt * 128 + kb);
            *(uint4*)((char*)ldsW + swz(o)) = db;
        }
        __syncthreads();
        #pragma unroll
        for (int kk = 0; kk < 2; ++kk) {
            const uint32_t kb = (uint32_t)((kk * 32 + (l >> 4) * 8) * 2);
            const uint32_t ar = (uint32_t)(wr + (l & 15));
            const s16x8 af = *(const s16x8*)((const char*)ldsA + swz(ar * 128 + kb));
            #pragma unroll
            for (int j = 0; j < 4; ++j) {
                const uint32_t br = (uint32_t)(j * 16 + (l & 15));
                const s16x8 bw = *(const s16x8*)((const char*)ldsW + swz(br * 128 + kb));
                acc[j] = __builtin_amdgcn_mfma_f32_16x16x32_bf16(af, bw, acc[j], 0, 0, 0);
            }
        }
        __syncthreads();
    }
    #pragma unroll
    for (int j = 0; j < 4; ++j)
        #pragma unroll
        for (int r = 0; r < 4; ++r) {
            const int row = wr + (l >> 4) * 4 + r;
            const int col = j * 16 + (l & 15);
            out[(size_t)(b0 + row) * Cn + col] = acc[j][r];
        }
}

// ---------------------------------------------------------------------------
extern "C" void kernel_launch(void* const* d_in, const int* in_sizes, int n_in,
                              void* d_out, int out_size, void* d_ws, size_t ws_size,
                              hipStream_t stream) {
    const float* self_feats = (const float*)d_in[0];
    const float* neigh      = (const float*)d_in[1];
    const float* mask       = (const float*)d_in[2];
    const float* a          = (const float*)d_in[3];
    const float* enc_w      = (const float*)d_in[4];
    const float* out_w      = (const float*)d_in[5];
    float* out = (float*)d_out;

    char* ws = (char*)d_ws;
    size_t off = 0;
    auto alloc = [&](size_t bytes) { char* p = ws + off; off += (bytes + 255) & ~(size_t)255; return p; };
    float*    Upart   = (float*)alloc((size_t)4 * 2 * Bn * Fn * 4); // 32 MB (4 K-chunks x 2 heads)
    float*    Z4      = (float*)alloc((size_t)4 * 2 * Bn * 4);      // 128 KB
    float*    x       = (float*)alloc((size_t)2 * Bn * 4);
    float*    y       = (float*)alloc((size_t)2 * Mn * 4);
    char*     neighTg = (char*)alloc((size_t)Fn * Mn * 2);          // 4 MB, tiled+swizzled
    uint16_t* self_bf = (uint16_t*)alloc((size_t)Bn * Fn * 2);      // 2 MB
    uint16_t* agg_bf  = (uint16_t*)alloc((size_t)2 * Bn * Fn * 2);  // 4 MB
    uint16_t* enc     = (uint16_t*)alloc((size_t)Bn * 512 * 2);     // 4 MB
    uint16_t* enc_wT  = (uint16_t*)alloc((size_t)2 * HIDn * 512 * 2);
    uint16_t* out_wT  = (uint16_t*)alloc((size_t)Cn * 512 * 2);

    k_prep_xy<<<(Bn + Mn) / 4, 256, 0, stream>>>(self_feats, neigh, a, x, y, self_bf);
    k_tn<<<dim3(Mn / 32, Fn / 32), 256, 0, stream>>>(neigh, neighTg);
    k_prep_w<<<(2 * HIDn * 512 + Cn * 512) / 256, 256, 0, stream>>>(enc_w, out_w, enc_wT, out_wT);
    k_main<<<dim3(Bn / 64, 4), 512, 0, stream>>>(mask, x, y, neighTg, Upart, Z4);
    k_agg<<<(2 * Bn * Fn / 8) / 256, 256, 0, stream>>>(Upart, Z4, agg_bf);
    k_enc<<<dim3(Bn / 128, 2, 2), 512, 0, stream>>>(self_bf, agg_bf, enc_wT, enc);
    k_out<<<Bn / 64, 256, 0, stream>>>(enc, out_wT, out);
}